// Round 2
// baseline (498.292 us; speedup 1.0000x reference)
//
#include <hip/hip_runtime.h>
#include <hip/hip_bf16.h>

// B=2, T=4 -> 8 clouds/side, N=16384 pts, 3 coords. Pads contribute 0 to both
// sum and count, so only real points are processed.
#define NPTS   16384
#define NCLOUD 16          // 8 output + 8 target clouds
#define NJOBS  16          // 8 (bt) x 2 (direction)
#define BLK    256
#define NQ     8           // queries per thread
#define QB     (BLK * NQ)  // 2048 queries per block
#define QBLOCKS (NPTS / QB)        // 8
#define KSPLIT  8
#define KPS     (NPTS / KSPLIT)    // 2048 keys per split
#define KU      8          // key unroll (keys live in SGPRs via uniform loads)

// monotonic float<->int mapping so signed-int atomicMin == float min
__device__ __forceinline__ int f2key(float f) {
    int b = __float_as_int(f);
    return (b >= 0) ? b : (b ^ 0x7fffffff);
}
__device__ __forceinline__ float key2f(int k) {
    int b = (k >= 0) ? k : (k ^ 0x7fffffff);
    return __int_as_float(b);
}

// pack keys as (x, y, z, |k|^2) so pass1's inner loop is 3 FMA + 0.5 min3/pair
__global__ __launch_bounds__(BLK)
void cham_pack(const float* __restrict__ op, const float* __restrict__ tp,
               float4* __restrict__ pk) {
    const int g = blockIdx.x * BLK + threadIdx.x;   // 0 .. NCLOUD*NPTS-1
    const int c = g >> 14;                          // /16384
    const int i = g & (NPTS - 1);
    const float* src = (c < 8) ? (op + (size_t)c * NPTS * 3)
                               : (tp + (size_t)(c - 8) * NPTS * 3);
    const float x = src[i * 3 + 0];
    const float y = src[i * 3 + 1];
    const float z = src[i * 3 + 2];
    pk[g] = make_float4(x, y, z, fmaf(x, x, fmaf(y, y, z * z)));
}

template<bool PACKED>
__global__ __launch_bounds__(BLK, 4)
void cham_pass1(const float* __restrict__ op, const float* __restrict__ tp,
                const float4* __restrict__ pk, int* __restrict__ wmin) {
    const int bid = blockIdx.x;
    const int job = bid >> 6;         // 64 blocks per job (8 qb x 8 ks)
    const int rem = bid & 63;
    const int qb  = rem >> 3;
    const int ks  = rem & 7;
    const int bt  = job >> 1;
    const int dir = job & 1;

    const float* qp = (dir == 0) ? (op + (size_t)bt * NPTS * 3)
                                 : (tp + (size_t)bt * NPTS * 3);
    const int tid = threadIdx.x;

    // this thread's 8 queries: keep -2*q in VGPRs
    float qsx[NQ], qsy[NQ], qsz[NQ], m[NQ];
    const float* q0 = qp + (size_t)qb * QB * 3;
    #pragma unroll
    for (int q = 0; q < NQ; ++q) {
        const int qi = q * BLK + tid;
        const float x = q0[qi * 3 + 0];
        const float y = q0[qi * 3 + 1];
        const float z = q0[qi * 3 + 2];
        qsx[q] = -2.0f * x; qsy[q] = -2.0f * y; qsz[q] = -2.0f * z;
        m[q] = 3.0e38f;
    }

    float kx[KU], ky[KU], kz[KU], kw[KU];

    if (PACKED) {
        const int kcloud = (dir == 0) ? (8 + bt) : bt;
        const float4* kp = pk + (size_t)kcloud * NPTS + (size_t)ks * KPS;
        for (int j = 0; j < KPS; j += KU) {
            // wave-uniform address + __restrict__ => scalar s_load path,
            // keys live in SGPRs (1 SGPR operand per FMA is legal)
            #pragma unroll
            for (int u = 0; u < KU; ++u) {
                const float4 t = kp[j + u];
                kx[u] = t.x; ky[u] = t.y; kz[u] = t.z; kw[u] = t.w;
            }
            #pragma unroll
            for (int q = 0; q < NQ; ++q) {
                #pragma unroll
                for (int u = 0; u < KU; u += 2) {
                    const float da = fmaf(qsx[q], kx[u],
                                     fmaf(qsy[q], ky[u],
                                     fmaf(qsz[q], kz[u], kw[u])));
                    const float db = fmaf(qsx[q], kx[u + 1],
                                     fmaf(qsy[q], ky[u + 1],
                                     fmaf(qsz[q], kz[u + 1], kw[u + 1])));
                    m[q] = fminf(m[q], fminf(da, db));   // -> v_min3_f32
                }
            }
        }
    } else {
        // fallback if ws too small for the pack: raw coords, k2 on the fly
        const float* kp = ((dir == 0) ? (tp + (size_t)bt * NPTS * 3)
                                      : (op + (size_t)bt * NPTS * 3))
                          + (size_t)ks * KPS * 3;
        for (int j = 0; j < KPS; j += KU) {
            #pragma unroll
            for (int u = 0; u < KU; ++u) {
                const float x = kp[(j + u) * 3 + 0];
                const float y = kp[(j + u) * 3 + 1];
                const float z = kp[(j + u) * 3 + 2];
                kx[u] = x; ky[u] = y; kz[u] = z;
                kw[u] = fmaf(x, x, fmaf(y, y, z * z));
            }
            #pragma unroll
            for (int q = 0; q < NQ; ++q) {
                #pragma unroll
                for (int u = 0; u < KU; u += 2) {
                    const float da = fmaf(qsx[q], kx[u],
                                     fmaf(qsy[q], ky[u],
                                     fmaf(qsz[q], kz[u], kw[u])));
                    const float db = fmaf(qsx[q], kx[u + 1],
                                     fmaf(qsy[q], ky[u + 1],
                                     fmaf(qsz[q], kz[u + 1], kw[u + 1])));
                    m[q] = fminf(m[q], fminf(da, db));
                }
            }
        }
    }

    int* wj = wmin + job * NPTS + qb * QB;
    #pragma unroll
    for (int q = 0; q < NQ; ++q) {
        atomicMin(&wj[q * BLK + tid], f2key(m[q]));
    }
}

__global__ __launch_bounds__(BLK)
void cham_pass2(const float* __restrict__ op, const float* __restrict__ tp,
                const int* __restrict__ wmin, float* __restrict__ ws2) {
    const int job  = blockIdx.x >> 2;   // 4 blocks per job
    const int part = blockIdx.x & 3;
    const int bt  = job >> 1;
    const int dir = job & 1;
    const float* qp = (dir == 0) ? (op + (size_t)bt * NPTS * 3)
                                 : (tp + (size_t)bt * NPTS * 3);
    const int tid = threadIdx.x;

    float S = 0.0f, P = 0.0f;
    const int lo = part * (NPTS / 4), hi = lo + (NPTS / 4);
    for (int i = lo + tid; i < hi; i += BLK) {
        const float x = qp[i * 3 + 0];
        const float y = qp[i * 3 + 1];
        const float z = qp[i * 3 + 2];
        const float q2 = fmaf(x, x, fmaf(y, y, z * z));
        const float d = fmaxf(q2 + key2f(wmin[job * NPTS + i]), 0.0f);
        S += d;
        P += (d > 0.0f) ? 1.0f : 0.0f;
    }

    #pragma unroll
    for (int o = 32; o > 0; o >>= 1) {
        S += __shfl_down(S, o, 64);
        P += __shfl_down(P, o, 64);
    }
    __shared__ float sS[4], sP[4];
    const int wv = tid >> 6;
    if ((tid & 63) == 0) { sS[wv] = S; sP[wv] = P; }
    __syncthreads();
    if (tid == 0) {
        atomicAdd(&ws2[job * 2 + 0], sS[0] + sS[1] + sS[2] + sS[3]);
        atomicAdd(&ws2[job * 2 + 1], sP[0] + sP[1] + sP[2] + sP[3]);
    }
}

__global__ void cham_pass3(const float* __restrict__ ws2, float* __restrict__ out) {
    __shared__ float dc[8];
    const int t = threadIdx.x;
    if (t < 8) {
        const float s0 = ws2[(t * 2 + 0) * 2 + 0];
        const float p0 = ws2[(t * 2 + 0) * 2 + 1];
        const float s1 = ws2[(t * 2 + 1) * 2 + 0];
        const float p1 = ws2[(t * 2 + 1) * 2 + 1];
        dc[t] = s0 / p0 + s1 / p1;
    }
    __syncthreads();
    if (t < 8) out[4 + t] = dc[t];            // tensor (T=4, B=2) row-major
    if (t < 4) out[t] = 0.5f * (dc[2 * t] + dc[2 * t + 1]);  // per-step mean
}

extern "C" void kernel_launch(void* const* d_in, const int* in_sizes, int n_in,
                              void* d_out, int out_size, void* d_ws, size_t ws_size,
                              hipStream_t stream) {
    const float* op = (const float*)d_in[0];
    const float* tp = (const float*)d_in[1];

    const size_t wmin_bytes = (size_t)NJOBS * NPTS * sizeof(int);      // 1 MiB
    const size_t ws2_off    = wmin_bytes;
    const size_t pk_off     = ws2_off + 256;                            // 16B-aligned
    const size_t pk_bytes   = (size_t)NCLOUD * NPTS * sizeof(float4);   // 4 MiB

    int*    wmin = (int*)d_ws;
    float*  ws2  = (float*)((char*)d_ws + ws2_off);
    float4* pk   = (float4*)((char*)d_ws + pk_off);
    float*  out  = (float*)d_out;

    hipMemsetAsync(wmin, 0x7F, wmin_bytes, stream);   // huge positive int-mapped float
    hipMemsetAsync(ws2, 0, (size_t)NJOBS * 2 * sizeof(float), stream);

    const bool packed = ws_size >= pk_off + pk_bytes;
    if (packed) {
        cham_pack<<<NCLOUD * NPTS / BLK, BLK, 0, stream>>>(op, tp, pk);
        cham_pass1<true><<<NJOBS * QBLOCKS * KSPLIT, BLK, 0, stream>>>(op, tp, pk, wmin);
    } else {
        cham_pass1<false><<<NJOBS * QBLOCKS * KSPLIT, BLK, 0, stream>>>(op, tp, pk, wmin);
    }
    cham_pass2<<<NJOBS * 4, BLK, 0, stream>>>(op, tp, wmin, ws2);
    cham_pass3<<<1, 64, 0, stream>>>(ws2, out);
}

// Round 3
// 259.287 us; speedup vs baseline: 1.9218x; 1.9218x over previous
//
#include <hip/hip_runtime.h>
#include <hip/hip_bf16.h>

// B=2, T=4 -> 8 clouds/side, N=16384 pts. Pads contribute 0 to sum and count,
// so only real points are processed (pad-key distances ~3e6 never win the min).
#define NPTS   16384
#define NCLOUD 16
#define NJOBS  16
#define BLK    256

// ---- MFMA pass geometry ----
#define KSPLIT 2
#define NA     8                      // A fragments per wave -> 128 queries/wave
#define QPW    (NA * 16)              // 128
#define QPB    (QPW * 4)              // 512 queries per block (4 waves)
#define QBLOCKS (NPTS / QPB)          // 32
#define KPB    (NPTS / KSPLIT)        // 8192 keys per block
#define STAGE_KEYS 512
#define NSTAGES (KPB / STAGE_KEYS)    // 16
#define CPS    (STAGE_KEYS / 16)      // 32 chunks (16 keys each) per stage

typedef __attribute__((ext_vector_type(8))) short short8;
typedef __attribute__((ext_vector_type(4))) float f32x4;

__device__ __forceinline__ unsigned short f2bf(float x) {   // RNE f32->bf16
    unsigned u = __float_as_uint(x);
    u += 0x7fffu + ((u >> 16) & 1u);
    return (unsigned short)(u >> 16);
}
__device__ __forceinline__ float bf2f(unsigned short h) {
    return __uint_as_float(((unsigned)h) << 16);
}
__device__ __forceinline__ int f2key(float f) {
    int b = __float_as_int(f);
    return (b >= 0) ? b : (b ^ 0x7fffffff);
}
__device__ __forceinline__ float key2f(int k) {
    int b = (k >= 0) ? k : (k ^ 0x7fffffff);
    return __int_as_float(b);
}

// Pack each key into two 16B B-fragment records (bf16 split kh+kl, k2 3-way):
//   rec0 (K-slots 0-7):  [khx,khy,khz,khx,khy,khz,klx,kly]
//   rec1 (K-slots 8-15): [klz,klx,kly,klz,k2a,k2b,k2c,0]
// Layout per cloud: 1024 chunks x 512B; chunk = [16 x rec0][16 x rec1].
__global__ __launch_bounds__(BLK)
void cham_pack(const float* __restrict__ op, const float* __restrict__ tp,
               uint4* __restrict__ pk2) {
    const int gkey = blockIdx.x * BLK + threadIdx.x;     // 0 .. NCLOUD*NPTS-1
    const int c = gkey >> 14;
    const int i = gkey & (NPTS - 1);
    const float* src = (c < 8) ? (op + (size_t)c * NPTS * 3)
                               : (tp + (size_t)(c - 8) * NPTS * 3);
    const float x = src[i * 3 + 0];
    const float y = src[i * 3 + 1];
    const float z = src[i * 3 + 2];
    const unsigned khx = f2bf(x), khy = f2bf(y), khz = f2bf(z);
    const unsigned klx = f2bf(x - bf2f(khx));
    const unsigned kly = f2bf(y - bf2f(khy));
    const unsigned klz = f2bf(z - bf2f(khz));
    const float k2 = fmaf(x, x, fmaf(y, y, z * z));
    const unsigned k2a = f2bf(k2);
    float rres = k2 - bf2f(k2a);
    const unsigned k2b = f2bf(rres);
    rres -= bf2f(k2b);
    const unsigned k2c = f2bf(rres);

    uint4 r0, r1;
    r0.x = khx | (khy << 16); r0.y = khz | (khx << 16);
    r0.z = khy | (khz << 16); r0.w = klx | (kly << 16);
    r1.x = klz | (klx << 16); r1.y = kly | (klz << 16);
    r1.z = k2a | (k2b << 16); r1.w = k2c;

    const int chunk = i >> 4, slot = i & 15;
    const size_t base = (size_t)c * 32768 + (size_t)chunk * 32 + slot; // uint4 units
    pk2[base]      = r0;
    pk2[base + 16] = r1;
}

// A-fragment (per lane, query row = lane&15, K-group g = lane>>4):
//   g0: [sxh,syh,szh,sxl,syl,szl,sxh,syh]   g1: [szh,sxl,syl,szl,1,1,1,0]
//   g2,g3: zero (their B values are don't-care broadcasts)
// where s = -2*q split into bf16 hi/lo. acc = k2 - 2 q.k  (q2 added in pass2).
__global__ __launch_bounds__(BLK, 3)
void cham_mfma(const float* __restrict__ op, const float* __restrict__ tp,
               const uint4* __restrict__ pk2, int* __restrict__ wmin) {
    __shared__ uint4 smem[STAGE_KEYS * 2];   // 16 KiB

    const int bid  = blockIdx.x;
    const int job  = bid >> 6;               // 64 blocks/job = 32 qblk x 2 ks
    const int rem  = bid & 63;
    const int qblk = rem >> 1;
    const int ks   = rem & 1;
    const int bt   = job >> 1, dir = job & 1;
    const float* qp = (dir == 0) ? (op + (size_t)bt * NPTS * 3)
                                 : (tp + (size_t)bt * NPTS * 3);
    const int kcloud = (dir == 0) ? (8 + bt) : bt;

    const int tid  = threadIdx.x;
    const int lane = tid & 63, w = tid >> 6;
    const int col  = lane & 15, g = lane >> 4;

    short8 a[NA];
    float  m[NA][4];
    const unsigned short ONE = 0x3f80;   // bf16 1.0
    #pragma unroll
    for (int f = 0; f < NA; ++f) {
        const int qi = qblk * QPB + w * QPW + f * 16 + col;
        const float x = qp[qi * 3 + 0];
        const float y = qp[qi * 3 + 1];
        const float z = qp[qi * 3 + 2];
        const float sx = -2.0f * x, sy = -2.0f * y, sz = -2.0f * z;
        const unsigned short sxh = f2bf(sx), syh = f2bf(sy), szh = f2bf(sz);
        const unsigned short sxl = f2bf(sx - bf2f(sxh));
        const unsigned short syl = f2bf(sy - bf2f(syh));
        const unsigned short szl = f2bf(sz - bf2f(szh));
        short8 av;
        if (g == 0) {
            av = short8{(short)sxh, (short)syh, (short)szh, (short)sxl,
                        (short)syl, (short)szl, (short)sxh, (short)syh};
        } else if (g == 1) {
            av = short8{(short)szh, (short)sxl, (short)syl, (short)szl,
                        (short)ONE, (short)ONE, (short)ONE, (short)0};
        } else {
            av = short8{0, 0, 0, 0, 0, 0, 0, 0};
        }
        a[f] = av;
        m[f][0] = 3.0e38f; m[f][1] = 3.0e38f; m[f][2] = 3.0e38f; m[f][3] = 3.0e38f;
    }

    const uint4* kbase = pk2 + (size_t)kcloud * 32768 + (size_t)ks * (KPB / 16) * 32;
    const int ldsidx = (g & 1) * 16 + col;   // uint4 index within a chunk
    const f32x4 zero = {0.0f, 0.0f, 0.0f, 0.0f};

    for (int s = 0; s < NSTAGES; ++s) {
        __syncthreads();
        const uint4* src = kbase + (size_t)s * CPS * 32;
        #pragma unroll
        for (int i = 0; i < 4; ++i) smem[tid + BLK * i] = src[tid + BLK * i];
        __syncthreads();

        for (int cp = 0; cp < CPS / 2; ++cp) {
            const short8 b0 = *(const short8*)&smem[cp * 64 + ldsidx];
            const short8 b1 = *(const short8*)&smem[cp * 64 + 32 + ldsidx];
            f32x4 accA[NA], accB[NA];
            #pragma unroll
            for (int f = 0; f < NA; ++f)
                accA[f] = __builtin_amdgcn_mfma_f32_16x16x32_bf16(a[f], b0, zero, 0, 0, 0);
            #pragma unroll
            for (int f = 0; f < NA; ++f)
                accB[f] = __builtin_amdgcn_mfma_f32_16x16x32_bf16(a[f], b1, zero, 0, 0, 0);
            #pragma unroll
            for (int f = 0; f < NA; ++f) {
                #pragma unroll
                for (int r = 0; r < 4; ++r)
                    m[f][r] = fminf(fminf(m[f][r], accA[f][r]), accB[f][r]);  // v_min3
            }
        }
    }

    // D layout: col=lane&15 (key), row=(lane>>4)*4+reg (query). Reduce over cols.
    int* wj = wmin + job * NPTS + qblk * QPB + w * QPW;
    #pragma unroll
    for (int f = 0; f < NA; ++f) {
        #pragma unroll
        for (int r = 0; r < 4; ++r) {
            float v = m[f][r];
            v = fminf(v, __shfl_xor(v, 1, 64));
            v = fminf(v, __shfl_xor(v, 2, 64));
            v = fminf(v, __shfl_xor(v, 4, 64));
            v = fminf(v, __shfl_xor(v, 8, 64));
            if (col == 0) atomicMin(&wj[f * 16 + g * 4 + r], f2key(v));
        }
    }
}

// ---- fallback (ws too small for the 8 MiB pack): R1-style VALU kernel ----
#define FB_NQ 8
#define FB_QB (BLK * FB_NQ)
#define FB_KS 8
#define FB_KPS (NPTS / FB_KS)
__global__ __launch_bounds__(BLK, 4)
void cham_fb(const float* __restrict__ op, const float* __restrict__ tp,
             int* __restrict__ wmin) {
    const int bid = blockIdx.x;
    const int job = bid >> 6;
    const int rem = bid & 63;
    const int qb  = rem >> 3;
    const int ks  = rem & 7;
    const int bt  = job >> 1, dir = job & 1;
    const float* qp = (dir == 0) ? (op + (size_t)bt * NPTS * 3)
                                 : (tp + (size_t)bt * NPTS * 3);
    const int tid = threadIdx.x;
    float qsx[FB_NQ], qsy[FB_NQ], qsz[FB_NQ], m[FB_NQ];
    const float* q0 = qp + (size_t)qb * FB_QB * 3;
    #pragma unroll
    for (int q = 0; q < FB_NQ; ++q) {
        const int qi = q * BLK + tid;
        const float x = q0[qi * 3], y = q0[qi * 3 + 1], z = q0[qi * 3 + 2];
        qsx[q] = -2.0f * x; qsy[q] = -2.0f * y; qsz[q] = -2.0f * z;
        m[q] = 3.0e38f;
    }
    const float* kp = ((dir == 0) ? (tp + (size_t)bt * NPTS * 3)
                                  : (op + (size_t)bt * NPTS * 3)) + (size_t)ks * FB_KPS * 3;
    for (int j = 0; j < FB_KPS; j += 2) {
        const float ax = kp[j * 3], ay = kp[j * 3 + 1], az = kp[j * 3 + 2];
        const float bx = kp[j * 3 + 3], by = kp[j * 3 + 4], bz = kp[j * 3 + 5];
        const float aw = fmaf(ax, ax, fmaf(ay, ay, az * az));
        const float bw = fmaf(bx, bx, fmaf(by, by, bz * bz));
        #pragma unroll
        for (int q = 0; q < FB_NQ; ++q) {
            const float da = fmaf(qsx[q], ax, fmaf(qsy[q], ay, fmaf(qsz[q], az, aw)));
            const float db = fmaf(qsx[q], bx, fmaf(qsy[q], by, fmaf(qsz[q], bz, bw)));
            m[q] = fminf(m[q], fminf(da, db));
        }
    }
    int* wj = wmin + job * NPTS + qb * FB_QB;
    #pragma unroll
    for (int q = 0; q < FB_NQ; ++q) atomicMin(&wj[q * BLK + tid], f2key(m[q]));
}

__global__ __launch_bounds__(BLK)
void cham_pass2(const float* __restrict__ op, const float* __restrict__ tp,
                const int* __restrict__ wmin, float* __restrict__ ws2) {
    const int job  = blockIdx.x >> 2;
    const int part = blockIdx.x & 3;
    const int bt  = job >> 1, dir = job & 1;
    const float* qp = (dir == 0) ? (op + (size_t)bt * NPTS * 3)
                                 : (tp + (size_t)bt * NPTS * 3);
    const int tid = threadIdx.x;
    float S = 0.0f, P = 0.0f;
    const int lo = part * (NPTS / 4), hi = lo + (NPTS / 4);
    for (int i = lo + tid; i < hi; i += BLK) {
        const float x = qp[i * 3], y = qp[i * 3 + 1], z = qp[i * 3 + 2];
        const float q2 = fmaf(x, x, fmaf(y, y, z * z));
        const float d = fmaxf(q2 + key2f(wmin[job * NPTS + i]), 0.0f);
        S += d;
        P += (d > 0.0f) ? 1.0f : 0.0f;
    }
    #pragma unroll
    for (int o = 32; o > 0; o >>= 1) {
        S += __shfl_down(S, o, 64);
        P += __shfl_down(P, o, 64);
    }
    __shared__ float sS[4], sP[4];
    const int wv = tid >> 6;
    if ((tid & 63) == 0) { sS[wv] = S; sP[wv] = P; }
    __syncthreads();
    if (tid == 0) {
        atomicAdd(&ws2[job * 2 + 0], sS[0] + sS[1] + sS[2] + sS[3]);
        atomicAdd(&ws2[job * 2 + 1], sP[0] + sP[1] + sP[2] + sP[3]);
    }
}

__global__ void cham_pass3(const float* __restrict__ ws2, float* __restrict__ out) {
    __shared__ float dc[8];
    const int t = threadIdx.x;
    if (t < 8) {
        const float s0 = ws2[(t * 2 + 0) * 2 + 0];
        const float p0 = ws2[(t * 2 + 0) * 2 + 1];
        const float s1 = ws2[(t * 2 + 1) * 2 + 0];
        const float p1 = ws2[(t * 2 + 1) * 2 + 1];
        dc[t] = s0 / p0 + s1 / p1;
    }
    __syncthreads();
    if (t < 8) out[4 + t] = dc[t];                           // tensor (T,B) row-major
    if (t < 4) out[t] = 0.5f * (dc[2 * t] + dc[2 * t + 1]);  // per-step mean
}

extern "C" void kernel_launch(void* const* d_in, const int* in_sizes, int n_in,
                              void* d_out, int out_size, void* d_ws, size_t ws_size,
                              hipStream_t stream) {
    const float* op = (const float*)d_in[0];
    const float* tp = (const float*)d_in[1];

    const size_t wmin_bytes = (size_t)NJOBS * NPTS * sizeof(int);        // 1 MiB
    const size_t ws2_off = wmin_bytes;
    const size_t pk_off  = ws2_off + 256;
    const size_t pk_bytes = (size_t)NCLOUD * 32768 * sizeof(uint4);      // 8 MiB

    int*   wmin = (int*)d_ws;
    float* ws2  = (float*)((char*)d_ws + ws2_off);
    uint4* pk2  = (uint4*)((char*)d_ws + pk_off);
    float* out  = (float*)d_out;

    hipMemsetAsync(wmin, 0x7F, wmin_bytes, stream);   // +huge int-mapped float
    hipMemsetAsync(ws2, 0, (size_t)NJOBS * 2 * sizeof(float), stream);

    if (ws_size >= pk_off + pk_bytes) {
        cham_pack<<<NCLOUD * NPTS / BLK, BLK, 0, stream>>>(op, tp, pk2);
        cham_mfma<<<NJOBS * QBLOCKS * KSPLIT, BLK, 0, stream>>>(op, tp, pk2, wmin);
    } else {
        cham_fb<<<NJOBS * 64, BLK, 0, stream>>>(op, tp, wmin);
    }
    cham_pass2<<<NJOBS * 4, BLK, 0, stream>>>(op, tp, wmin, ws2);
    cham_pass3<<<1, 64, 0, stream>>>(ws2, out);
}

// Round 4
// 204.843 us; speedup vs baseline: 2.4326x; 1.2658x over previous
//
#include <hip/hip_runtime.h>
#include <hip/hip_bf16.h>

// B=2, T=4 -> 8 clouds/side, N=16384 pts. Pads contribute 0 to sum and count,
// so only real points are processed (pad-key distances ~3e6 never win the min).
#define NPTS   16384
#define NCLOUD 16
#define NJOBS  16
#define BLK    256

// ---- 32x32x16 MFMA pass geometry ----
#define NA      4                     // A fragments per wave -> 128 queries/wave
#define QPW     (NA * 32)             // 128
#define QPB     (QPW * 4)             // 512 queries per block (4 waves)
#define QBLOCKS (NPTS / QPB)          // 32
#define STAGE_KEYS 512
#define STAGE_U4   (STAGE_KEYS * 2)   // 1024 uint4 = 16 KiB (32B per key)
#define NSTAGES    (NPTS / STAGE_KEYS)        // 32 (KSPLIT=1: block sees all keys)
#define CPS        (STAGE_KEYS / 32)          // 16 chunks (32 keys each) per stage

typedef __attribute__((ext_vector_type(8)))  short short8;
typedef __attribute__((ext_vector_type(16))) float f32x16;

__device__ __forceinline__ unsigned short f2bf(float x) {   // RNE f32->bf16
    unsigned u = __float_as_uint(x);
    u += 0x7fffu + ((u >> 16) & 1u);
    return (unsigned short)(u >> 16);
}
__device__ __forceinline__ float bf2f(unsigned short h) {
    return __uint_as_float(((unsigned)h) << 16);
}
__device__ __forceinline__ int f2key(float f) {
    int b = __float_as_int(f);
    return (b >= 0) ? b : (b ^ 0x7fffffff);
}
__device__ __forceinline__ float key2f(int k) {
    int b = (k >= 0) ? k : (k ^ 0x7fffffff);
    return __int_as_float(b);
}

// Pack each key into two 16B B-fragment records (bf16 split kh+kl, k2 3-way):
//   rec0 (K-slots 0-7):  [khx,khy,khz,khx,khy,khz,klx,kly]   for lanes < 32
//   rec1 (K-slots 8-15): [klz,klx,kly,klz,k2a,k2b,k2c,0]     for lanes >= 32
// Per cloud: 512 chunks of 32 keys; chunk = [32 x rec0][32 x rec1] = 1 KiB.
// B-frag load is then exactly: uint4 at chunk_base + lane (linear, conflict-free).
__global__ __launch_bounds__(BLK)
void cham_pack(const float* __restrict__ op, const float* __restrict__ tp,
               uint4* __restrict__ pk2) {
    const int gkey = blockIdx.x * BLK + threadIdx.x;     // 0 .. NCLOUD*NPTS-1
    const int c = gkey >> 14;
    const int i = gkey & (NPTS - 1);
    const float* src = (c < 8) ? (op + (size_t)c * NPTS * 3)
                               : (tp + (size_t)(c - 8) * NPTS * 3);
    const float x = src[i * 3 + 0];
    const float y = src[i * 3 + 1];
    const float z = src[i * 3 + 2];
    const unsigned khx = f2bf(x), khy = f2bf(y), khz = f2bf(z);
    const unsigned klx = f2bf(x - bf2f(khx));
    const unsigned kly = f2bf(y - bf2f(khy));
    const unsigned klz = f2bf(z - bf2f(khz));
    const float k2 = fmaf(x, x, fmaf(y, y, z * z));
    const unsigned k2a = f2bf(k2);
    float rres = k2 - bf2f(k2a);
    const unsigned k2b = f2bf(rres);
    rres -= bf2f(k2b);
    const unsigned k2c = f2bf(rres);

    uint4 r0, r1;
    r0.x = khx | (khy << 16); r0.y = khz | (khx << 16);
    r0.z = khy | (khz << 16); r0.w = klx | (kly << 16);
    r1.x = klz | (klx << 16); r1.y = kly | (klz << 16);
    r1.z = k2a | (k2b << 16); r1.w = k2c;

    const int chunk = i >> 5, slot = i & 31;
    const size_t base = (size_t)c * 32768 + (size_t)chunk * 64 + slot; // uint4 units
    pk2[base]      = r0;
    pk2[base + 32] = r1;
}

// A-fragment (32x32x16: row = lane&31, K-group g = lane>>5, k = g*8+j):
//   g0: [sxh,syh,szh,sxl,syl,szl,sxh,syh]   g1: [szh,sxl,syl,szl,1,1,1,0]
// with s = -2*q split into bf16 hi/lo.  acc = k2 - 2 q.k  (q2 added in pass2).
__global__ __launch_bounds__(BLK, 2)
void cham_mfma(const float* __restrict__ op, const float* __restrict__ tp,
               const uint4* __restrict__ pk2, int* __restrict__ wmin) {
    __shared__ uint4 smem[STAGE_U4];   // 16 KiB

    const int bid  = blockIdx.x;
    const int job  = bid >> 5;               // 32 qblk per job
    const int qblk = bid & 31;
    const int bt   = job >> 1, dir = job & 1;
    const float* qp = (dir == 0) ? (op + (size_t)bt * NPTS * 3)
                                 : (tp + (size_t)bt * NPTS * 3);
    const int kcloud = (dir == 0) ? (8 + bt) : bt;

    const int tid  = threadIdx.x;
    const int lane = tid & 63, w = tid >> 6;
    const int col  = lane & 31, g = lane >> 5;

    short8 a[NA];
    f32x16 m[NA];
    const unsigned short ONE = 0x3f80;   // bf16 1.0
    #pragma unroll
    for (int f = 0; f < NA; ++f) {
        const int qi = qblk * QPB + w * QPW + f * 32 + col;
        const float x = qp[qi * 3 + 0];
        const float y = qp[qi * 3 + 1];
        const float z = qp[qi * 3 + 2];
        const float sx = -2.0f * x, sy = -2.0f * y, sz = -2.0f * z;
        const unsigned short sxh = f2bf(sx), syh = f2bf(sy), szh = f2bf(sz);
        const unsigned short sxl = f2bf(sx - bf2f(sxh));
        const unsigned short syl = f2bf(sy - bf2f(syh));
        const unsigned short szl = f2bf(sz - bf2f(szh));
        if (g == 0) {
            a[f] = short8{(short)sxh, (short)syh, (short)szh, (short)sxl,
                          (short)syl, (short)szl, (short)sxh, (short)syh};
        } else {
            a[f] = short8{(short)szh, (short)sxl, (short)syl, (short)szl,
                          (short)ONE, (short)ONE, (short)ONE, (short)0};
        }
        #pragma unroll
        for (int r = 0; r < 16; ++r) m[f][r] = 3.0e38f;
    }

    const uint4* kbase = pk2 + (size_t)kcloud * 32768;
    const f32x16 zero = {0.0f, 0.0f, 0.0f, 0.0f, 0.0f, 0.0f, 0.0f, 0.0f,
                         0.0f, 0.0f, 0.0f, 0.0f, 0.0f, 0.0f, 0.0f, 0.0f};

    for (int s = 0; s < NSTAGES; ++s) {
        __syncthreads();
        const uint4* src = kbase + (size_t)s * STAGE_U4;
        #pragma unroll
        for (int i = 0; i < STAGE_U4 / BLK; ++i)
            smem[tid + BLK * i] = src[tid + BLK * i];
        __syncthreads();

        #pragma unroll 2
        for (int cp = 0; cp < CPS / 2; ++cp) {
            const short8 b0 = *(const short8*)&smem[cp * 128 + lane];
            const short8 b1 = *(const short8*)&smem[cp * 128 + 64 + lane];
            #pragma unroll
            for (int f = 0; f < NA; ++f) {
                const f32x16 accA = __builtin_amdgcn_mfma_f32_32x32x16_bf16(a[f], b0, zero, 0, 0, 0);
                const f32x16 accB = __builtin_amdgcn_mfma_f32_32x32x16_bf16(a[f], b1, zero, 0, 0, 0);
                #pragma unroll
                for (int r = 0; r < 16; ++r)
                    m[f][r] = fminf(fminf(m[f][r], accA[r]), accB[r]);   // v_min3_f32
            }
        }
    }

    // D layout: col = lane&31 (key), row = (r&3) + 8*(r>>2) + 4*g (query).
    // Min over the 32 cols = butterfly over lane bits 0-4; rows don't mix.
    int* wj = wmin + job * NPTS + qblk * QPB + w * QPW;
    #pragma unroll
    for (int f = 0; f < NA; ++f) {
        #pragma unroll
        for (int r = 0; r < 16; ++r) {
            float v = m[f][r];
            v = fminf(v, __shfl_xor(v, 1, 64));
            v = fminf(v, __shfl_xor(v, 2, 64));
            v = fminf(v, __shfl_xor(v, 4, 64));
            v = fminf(v, __shfl_xor(v, 8, 64));
            v = fminf(v, __shfl_xor(v, 16, 64));
            if (col == 0)
                wj[f * 32 + (r & 3) + 8 * (r >> 2) + 4 * g] = f2key(v);  // plain store
        }
    }
}

// ---- fallback (ws too small for the 8 MiB pack): VALU kernel + atomicMin ----
#define FB_NQ 8
#define FB_QB (BLK * FB_NQ)
#define FB_KS 8
#define FB_KPS (NPTS / FB_KS)
__global__ __launch_bounds__(BLK, 4)
void cham_fb(const float* __restrict__ op, const float* __restrict__ tp,
             int* __restrict__ wmin) {
    const int bid = blockIdx.x;
    const int job = bid >> 6;
    const int rem = bid & 63;
    const int qb  = rem >> 3;
    const int ks  = rem & 7;
    const int bt  = job >> 1, dir = job & 1;
    const float* qp = (dir == 0) ? (op + (size_t)bt * NPTS * 3)
                                 : (tp + (size_t)bt * NPTS * 3);
    const int tid = threadIdx.x;
    float qsx[FB_NQ], qsy[FB_NQ], qsz[FB_NQ], m[FB_NQ];
    const float* q0 = qp + (size_t)qb * FB_QB * 3;
    #pragma unroll
    for (int q = 0; q < FB_NQ; ++q) {
        const int qi = q * BLK + tid;
        const float x = q0[qi * 3], y = q0[qi * 3 + 1], z = q0[qi * 3 + 2];
        qsx[q] = -2.0f * x; qsy[q] = -2.0f * y; qsz[q] = -2.0f * z;
        m[q] = 3.0e38f;
    }
    const float* kp = ((dir == 0) ? (tp + (size_t)bt * NPTS * 3)
                                  : (op + (size_t)bt * NPTS * 3)) + (size_t)ks * FB_KPS * 3;
    for (int j = 0; j < FB_KPS; j += 2) {
        const float ax = kp[j * 3], ay = kp[j * 3 + 1], az = kp[j * 3 + 2];
        const float bx = kp[j * 3 + 3], by = kp[j * 3 + 4], bz = kp[j * 3 + 5];
        const float aw = fmaf(ax, ax, fmaf(ay, ay, az * az));
        const float bw = fmaf(bx, bx, fmaf(by, by, bz * bz));
        #pragma unroll
        for (int q = 0; q < FB_NQ; ++q) {
            const float da = fmaf(qsx[q], ax, fmaf(qsy[q], ay, fmaf(qsz[q], az, aw)));
            const float db = fmaf(qsx[q], bx, fmaf(qsy[q], by, fmaf(qsz[q], bz, bw)));
            m[q] = fminf(m[q], fminf(da, db));
        }
    }
    int* wj = wmin + job * NPTS + qb * FB_QB;
    #pragma unroll
    for (int q = 0; q < FB_NQ; ++q) atomicMin(&wj[q * BLK + tid], f2key(m[q]));
}

__global__ __launch_bounds__(BLK)
void cham_pass2(const float* __restrict__ op, const float* __restrict__ tp,
                const int* __restrict__ wmin, float* __restrict__ ws2) {
    const int job  = blockIdx.x >> 2;
    const int part = blockIdx.x & 3;
    const int bt  = job >> 1, dir = job & 1;
    const float* qp = (dir == 0) ? (op + (size_t)bt * NPTS * 3)
                                 : (tp + (size_t)bt * NPTS * 3);
    const int tid = threadIdx.x;
    float S = 0.0f, P = 0.0f;
    const int lo = part * (NPTS / 4), hi = lo + (NPTS / 4);
    for (int i = lo + tid; i < hi; i += BLK) {
        const float x = qp[i * 3], y = qp[i * 3 + 1], z = qp[i * 3 + 2];
        const float q2 = fmaf(x, x, fmaf(y, y, z * z));
        const float d = fmaxf(q2 + key2f(wmin[job * NPTS + i]), 0.0f);
        S += d;
        P += (d > 0.0f) ? 1.0f : 0.0f;
    }
    #pragma unroll
    for (int o = 32; o > 0; o >>= 1) {
        S += __shfl_down(S, o, 64);
        P += __shfl_down(P, o, 64);
    }
    __shared__ float sS[4], sP[4];
    const int wv = tid >> 6;
    if ((tid & 63) == 0) { sS[wv] = S; sP[wv] = P; }
    __syncthreads();
    if (tid == 0) {
        atomicAdd(&ws2[job * 2 + 0], sS[0] + sS[1] + sS[2] + sS[3]);
        atomicAdd(&ws2[job * 2 + 1], sP[0] + sP[1] + sP[2] + sP[3]);
    }
}

__global__ void cham_pass3(const float* __restrict__ ws2, float* __restrict__ out) {
    __shared__ float dc[8];
    const int t = threadIdx.x;
    if (t < 8) {
        const float s0 = ws2[(t * 2 + 0) * 2 + 0];
        const float p0 = ws2[(t * 2 + 0) * 2 + 1];
        const float s1 = ws2[(t * 2 + 1) * 2 + 0];
        const float p1 = ws2[(t * 2 + 1) * 2 + 1];
        dc[t] = s0 / p0 + s1 / p1;
    }
    __syncthreads();
    if (t < 8) out[4 + t] = dc[t];                           // tensor (T,B) row-major
    if (t < 4) out[t] = 0.5f * (dc[2 * t] + dc[2 * t + 1]);  // per-step mean
}

extern "C" void kernel_launch(void* const* d_in, const int* in_sizes, int n_in,
                              void* d_out, int out_size, void* d_ws, size_t ws_size,
                              hipStream_t stream) {
    const float* op = (const float*)d_in[0];
    const float* tp = (const float*)d_in[1];

    const size_t wmin_bytes = (size_t)NJOBS * NPTS * sizeof(int);        // 1 MiB
    const size_t ws2_off = wmin_bytes;
    const size_t pk_off  = ws2_off + 256;
    const size_t pk_bytes = (size_t)NCLOUD * 32768 * sizeof(uint4);      // 8 MiB

    int*   wmin = (int*)d_ws;
    float* ws2  = (float*)((char*)d_ws + ws2_off);
    uint4* pk2  = (uint4*)((char*)d_ws + pk_off);
    float* out  = (float*)d_out;

    hipMemsetAsync(ws2, 0, (size_t)NJOBS * 2 * sizeof(float), stream);

    if (ws_size >= pk_off + pk_bytes) {
        // KSPLIT=1: every wmin slot is written exactly once by a plain store,
        // so no wmin memset and no atomics in the hot kernel.
        cham_pack<<<NCLOUD * NPTS / BLK, BLK, 0, stream>>>(op, tp, pk2);
        cham_mfma<<<NJOBS * QBLOCKS, BLK, 0, stream>>>(op, tp, pk2, wmin);
    } else {
        hipMemsetAsync(wmin, 0x7F, wmin_bytes, stream);   // +huge int-mapped float
        cham_fb<<<NJOBS * 64, BLK, 0, stream>>>(op, tp, wmin);
    }
    cham_pass2<<<NJOBS * 4, BLK, 0, stream>>>(op, tp, wmin, ws2);
    cham_pass3<<<1, 64, 0, stream>>>(ws2, out);
}